// Round 1
// baseline (131.363 us; speedup 1.0000x reference)
//
#include <hip/hip_runtime.h>

// Problem constants (reference: N=4, T=128, F=512, EMBED=128, NLOC=360)
#define NT 512    // N*T
#define FD 512    // F (freq bins)
#define ED 128    // EMBED
#define LD 360    // NLOC

// ---------------------------------------------------------------------------
// Key algebraic fact: in the reference,
//   out = einsum("neqk,ntve->ntqe", attention, values)
// has NO shared summed index between the operands: k is summed only over
// attention (softmax axis => sums to 1), v only over values. Hence
//   out[n,t,q,e] = sum_v values[n,t,v,e]   (independent of q / query / key).
// Final result[n,t,q,l] = sum_e Wo[l,e] * sum_c (sum_v value[n,t,v,c]) Wv[e,c] + bo[l]
// broadcast over q. Memory-bound: read value (128MB) + write out (377MB).
// ---------------------------------------------------------------------------

// Kernel B: per (n,t) row: reduce over v, project through Wv then Wo, add bias.
// Produces G[nt][LD] (f32) in workspace.
__global__ __launch_bounds__(256) void kB_reduce_project(
    const float* __restrict__ value,   // [NT][FD][ED]
    const float* __restrict__ Wv,      // [ED][ED]  (row e, col c)
    const float* __restrict__ Wo,      // [LD][ED]  (row l, col e)
    const float* __restrict__ bo,      // [LD]
    float* __restrict__ G)             // [NT][LD]
{
    const int nt  = blockIdx.x;
    const int tid = threadIdx.x;

    __shared__ float sRed[8][ED];   // partial v-sums, 4 KB
    __shared__ float sS[ED];        // S[c] = sum_v value[nt][v][c]
    __shared__ float sP[ED];        // P[e] = sum_c S[c] * Wv[e][c]

    const float* base = value + (size_t)nt * FD * ED;

    // Phase 1: v-reduction. lane group covers one 512B row per 32 lanes.
    const int c4 = (tid & 31) * 4;  // f32 column group
    const int vg = tid >> 5;        // 0..7
    float4 acc; acc.x = 0.f; acc.y = 0.f; acc.z = 0.f; acc.w = 0.f;
    for (int v = vg; v < FD; v += 8) {
        const float4 r = *(const float4*)&base[(size_t)v * ED + c4];
        acc.x += r.x; acc.y += r.y; acc.z += r.z; acc.w += r.w;
    }
    *(float4*)&sRed[vg][c4] = acc;
    __syncthreads();

    if (tid < ED) {
        float s = 0.f;
        #pragma unroll
        for (int g = 0; g < 8; ++g) s += sRed[g][tid];
        sS[tid] = s;
    }
    __syncthreads();

    // Phase 2: P[e] = <S, Wv[e,:]>   (Wv is 64KB, L2-resident)
    if (tid < ED) {
        const float* wr = Wv + (size_t)tid * ED;
        float p = 0.f;
        #pragma unroll
        for (int c = 0; c < ED; c += 4) {
            const float4 w4 = *(const float4*)&wr[c];
            const float4 s4 = *(const float4*)&sS[c];
            p += w4.x * s4.x + w4.y * s4.y + w4.z * s4.z + w4.w * s4.w;
        }
        sP[tid] = p;
    }
    __syncthreads();

    // Phase 3: G[l] = bo[l] + <Wo[l,:], P>
    for (int l = tid; l < LD; l += 256) {
        const float* wr = Wo + (size_t)l * ED;
        float g = bo[l];
        #pragma unroll
        for (int e = 0; e < ED; e += 4) {
            const float4 w4 = *(const float4*)&wr[e];
            const float4 p4 = *(const float4*)&sP[e];
            g += w4.x * p4.x + w4.y * p4.y + w4.z * p4.z + w4.w * p4.w;
        }
        G[(size_t)nt * LD + l] = g;
    }
}

// Kernel C: broadcast each G row across the 512 q positions.
// grid (NT, FD/64); each block writes 64 output rows of 1440B (16B aligned: 90 float4).
__global__ __launch_bounds__(256) void kC_broadcast(
    const float* __restrict__ G,       // [NT][LD]
    float* __restrict__ out)           // [NT][FD][LD]
{
    const int nt  = blockIdx.x;   // 0..511
    const int qc  = blockIdx.y;   // 0..7
    const int tid = threadIdx.x;

    __shared__ float sG[LD];
    for (int l = tid; l < LD; l += 256) sG[l] = G[(size_t)nt * LD + l];
    __syncthreads();

    const float4* sG4 = (const float4*)sG;                 // 90 float4
    float4* ob4 = (float4*)(out + ((size_t)nt * FD + (size_t)qc * 64) * LD);
    // 64 rows * 90 float4 = 5760 vec stores per block, fully coalesced.
    for (int idx = tid; idx < 64 * 90; idx += 256) {
        const int r = idx % 90;   // constant divisor -> magic multiply
        ob4[idx] = sG4[r];
    }
}

extern "C" void kernel_launch(void* const* d_in, const int* in_sizes, int n_in,
                              void* d_out, int out_size, void* d_ws, size_t ws_size,
                              hipStream_t stream) {
    (void)in_sizes; (void)n_in; (void)out_size; (void)ws_size;
    // setup_inputs order: value, key, query, Wv, Wk, Wq, Wo, bo
    const float* value = (const float*)d_in[0];
    const float* Wv    = (const float*)d_in[3];
    const float* Wo    = (const float*)d_in[6];
    const float* bo    = (const float*)d_in[7];
    float* out = (float*)d_out;
    float* G   = (float*)d_ws;   // needs NT*LD*4 = 737,280 bytes

    kB_reduce_project<<<dim3(NT), dim3(256), 0, stream>>>(value, Wv, Wo, bo, G);
    kC_broadcast<<<dim3(NT, FD / 64), dim3(256), 0, stream>>>(G, out);
}

// Round 2
// 130.366 us; speedup vs baseline: 1.0076x; 1.0076x over previous
//
#include <hip/hip_runtime.h>

// Problem constants (reference: N=4, T=128, F=512, EMBED=128, NLOC=360)
#define NT 512    // N*T
#define FD 512    // F (freq bins)
#define ED 128    // EMBED
#define LD 360    // NLOC
#define VCH 8     // v-chunks per nt (grid-parallel partial reduction)

// ---------------------------------------------------------------------------
// Algebraic fact: einsum("neqk,ntve->ntqe", attention, values) has no shared
// contraction index: softmax over k sums to 1, so
//   out[n,t,q,:] = Wo @ (Wv @ sum_v value[n,t,v,:]) + bo,  independent of q.
// Memory-bound: read value (128MB) + write out (377MB). Floor ~75us @6.8TB/s.
// ---------------------------------------------------------------------------

// K1: grid (NT, VCH). Each block reduces 64 contiguous v-rows (32 KB) into
// partial[nt][y][ED]. Pure streaming read, 4096 blocks -> full occupancy.
__global__ __launch_bounds__(256) void k1_partial_reduce(
    const float* __restrict__ value,   // [NT][FD][ED]
    float* __restrict__ partial)       // [NT][VCH][ED]
{
    const int nt  = blockIdx.x;
    const int y   = blockIdx.y;
    const int tid = threadIdx.x;

    const int c4 = (tid & 31) * 4;   // column group (f32 index)
    const int vg = tid >> 5;         // 0..7 row subgroup

    const float* base = value + ((size_t)nt * FD + (size_t)y * 64) * ED;

    float4 acc; acc.x = 0.f; acc.y = 0.f; acc.z = 0.f; acc.w = 0.f;
    #pragma unroll
    for (int i = 0; i < 8; ++i) {
        const float4 r = *(const float4*)&base[(size_t)(vg + 8 * i) * ED + c4];
        acc.x += r.x; acc.y += r.y; acc.z += r.z; acc.w += r.w;
    }

    __shared__ float sRed[8][ED];    // 4 KB
    *(float4*)&sRed[vg][c4] = acc;
    __syncthreads();

    if (tid < ED) {
        float s = 0.f;
        #pragma unroll
        for (int g = 0; g < 8; ++g) s += sRed[g][tid];
        partial[((size_t)nt * VCH + y) * ED + tid] = s;
    }
}

// K2: grid (NT). Finish reduction, project through Wv then Wo (+bo) -> G.
// Tiny: reads 2MB partials + L2-resident weights, writes 737KB.
__global__ __launch_bounds__(256) void k2_project(
    const float* __restrict__ partial, // [NT][VCH][ED]
    const float* __restrict__ Wv,      // [ED][ED]
    const float* __restrict__ Wo,      // [LD][ED]
    const float* __restrict__ bo,      // [LD]
    float* __restrict__ G)             // [NT][LD]
{
    const int nt  = blockIdx.x;
    const int tid = threadIdx.x;

    __shared__ float sS[ED];
    __shared__ float sP[ED];

    if (tid < ED) {
        const float* pr = partial + (size_t)nt * VCH * ED + tid;
        float s = 0.f;
        #pragma unroll
        for (int y = 0; y < VCH; ++y) s += pr[(size_t)y * ED];
        sS[tid] = s;
    }
    __syncthreads();

    if (tid < ED) {
        const float* wr = Wv + (size_t)tid * ED;
        float p = 0.f;
        #pragma unroll
        for (int c = 0; c < ED; c += 4) {
            const float4 w4 = *(const float4*)&wr[c];
            const float4 s4 = *(const float4*)&sS[c];
            p += w4.x * s4.x + w4.y * s4.y + w4.z * s4.z + w4.w * s4.w;
        }
        sP[tid] = p;
    }
    __syncthreads();

    for (int l = tid; l < LD; l += 256) {
        const float* wr = Wo + (size_t)l * ED;
        float g = bo[l];
        #pragma unroll
        for (int e = 0; e < ED; e += 4) {
            const float4 w4 = *(const float4*)&wr[e];
            const float4 p4 = *(const float4*)&sP[e];
            g += w4.x * p4.x + w4.y * p4.y + w4.z * p4.z + w4.w * p4.w;
        }
        G[(size_t)nt * LD + l] = g;
    }
}

// K3: broadcast each G row across the 512 q positions (377MB of writes).
__global__ __launch_bounds__(256) void k3_broadcast(
    const float* __restrict__ G,       // [NT][LD]
    float* __restrict__ out)           // [NT][FD][LD]
{
    const int nt  = blockIdx.x;   // 0..511
    const int qc  = blockIdx.y;   // 0..7
    const int tid = threadIdx.x;

    __shared__ float sG[LD];
    for (int l = tid; l < LD; l += 256) sG[l] = G[(size_t)nt * LD + l];
    __syncthreads();

    const float4* sG4 = (const float4*)sG;                 // 90 float4
    float4* ob4 = (float4*)(out + ((size_t)nt * FD + (size_t)qc * 64) * LD);
    // 64 rows * 90 float4 = 5760 coalesced vec stores per block.
    for (int idx = tid; idx < 64 * 90; idx += 256) {
        const int r = idx % 90;   // constant divisor -> magic multiply
        ob4[idx] = sG4[r];
    }
}

extern "C" void kernel_launch(void* const* d_in, const int* in_sizes, int n_in,
                              void* d_out, int out_size, void* d_ws, size_t ws_size,
                              hipStream_t stream) {
    (void)in_sizes; (void)n_in; (void)out_size; (void)ws_size;
    // setup_inputs order: value, key, query, Wv, Wk, Wq, Wo, bo
    const float* value = (const float*)d_in[0];
    const float* Wv    = (const float*)d_in[3];
    const float* Wo    = (const float*)d_in[6];
    const float* bo    = (const float*)d_in[7];
    float* out = (float*)d_out;

    float* partial = (float*)d_ws;                       // NT*VCH*ED*4 = 2 MB
    float* G       = partial + (size_t)NT * VCH * ED;    // NT*LD*4 = 737 KB

    k1_partial_reduce<<<dim3(NT, VCH), dim3(256), 0, stream>>>(value, partial);
    k2_project<<<dim3(NT), dim3(256), 0, stream>>>(partial, Wv, Wo, bo, G);
    k3_broadcast<<<dim3(NT, FD / 64), dim3(256), 0, stream>>>(G, out);
}

// Round 3
// 112.364 us; speedup vs baseline: 1.1691x; 1.1602x over previous
//
#include <hip/hip_runtime.h>

// Problem constants (reference: N=4, T=128, F=512, EMBED=128, NLOC=360)
#define NT 512    // N*T
#define FD 512    // F (freq bins / q positions)
#define ED 128    // EMBED
#define LD 360    // NLOC

// ---------------------------------------------------------------------------
// Algebraic fact: einsum("neqk,ntve->ntqe", attention, values) has no shared
// contraction index between its operands: softmax over k sums to 1, so
//   out[n,t,q,:] = Wo @ (Wv @ sum_v value[n,t,v,:]) + bo, independent of q,
//   query, key, Wq, Wk.  (Validated: rounds 1-2 passed, absmax 0.125 << 0.76.)
// Memory-bound: read value (128 MB) + write out (377 MB) ~= 505 MB -> ~73 us
// floor at the 6.9 TB/s the harness's own fill kernels sustain.
//
// Round-2 lesson: 3-kernel split leaves ~40 us of launch/bubble overhead and
// the store loop paid a dependent LDS read + integer mod per store. This
// round: ONE fused kernel; stores are register-sourced (row image in VGPRs,
// loaded from LDS once per wave), matching the fill kernel's structure.
// ---------------------------------------------------------------------------

__global__ __launch_bounds__(512) void fused_attn(
    const float* __restrict__ value,   // [NT][FD][ED]
    const float* __restrict__ Wv,      // [ED][ED]  (row e, col c)
    const float* __restrict__ Wo,      // [LD][ED]  (row l, col e)
    const float* __restrict__ bo,      // [LD]
    float* __restrict__ out)           // [NT][FD][LD]
{
    const int nt  = blockIdx.x;
    const int tid = threadIdx.x;

    __shared__ float sRed[16][ED];   // 8 KB partial v-sums
    __shared__ float sS[ED];         // S[c] = sum_v value[nt][v][c]
    __shared__ float sP[ED];         // P[e] = <Wv[e,:], S>
    __shared__ float sG[LD];         // G[l] = <Wo[l,:], P> + bo[l]

    // ---- Phase 1: v-reduction (read 256 KB, fully coalesced) ----
    const int c4 = (tid & 31) * 4;   // f32 column group within a 512-B row
    const int vg = tid >> 5;         // 0..15 row subgroup
    const float* base = value + (size_t)nt * FD * ED;

    float4 acc; acc.x = 0.f; acc.y = 0.f; acc.z = 0.f; acc.w = 0.f;
    #pragma unroll 8
    for (int i = 0; i < 32; ++i) {   // rows vg, vg+16, ..., vg+496
        const float4 r = *(const float4*)&base[(size_t)(vg + 16 * i) * ED + c4];
        acc.x += r.x; acc.y += r.y; acc.z += r.z; acc.w += r.w;
    }
    *(float4*)&sRed[vg][c4] = acc;
    __syncthreads();

    if (tid < ED) {
        float s = 0.f;
        #pragma unroll
        for (int g = 0; g < 16; ++g) s += sRed[g][tid];
        sS[tid] = s;
    }
    __syncthreads();

    // ---- Phase 2: P = Wv * S  (Wv 64 KB, L2-resident across blocks) ----
    if (tid < ED) {
        const float* wr = Wv + (size_t)tid * ED;
        float p = 0.f;
        #pragma unroll
        for (int c = 0; c < ED; c += 4) {
            const float4 w4 = *(const float4*)&wr[c];
            const float4 s4 = *(const float4*)&sS[c];
            p += w4.x * s4.x + w4.y * s4.y + w4.z * s4.z + w4.w * s4.w;
        }
        sP[tid] = p;
    }
    __syncthreads();

    // ---- Phase 3: G = Wo * P + bo  (360 <= 512: one pass) ----
    if (tid < LD) {
        const float* wr = Wo + (size_t)tid * ED;
        float g = bo[tid];
        #pragma unroll
        for (int e = 0; e < ED; e += 4) {
            const float4 w4 = *(const float4*)&wr[e];
            const float4 p4 = *(const float4*)&sP[e];
            g += w4.x * p4.x + w4.y * p4.y + w4.z * p4.z + w4.w * p4.w;
        }
        sG[tid] = g;
    }
    __syncthreads();

    // ---- Phase 4: broadcast-store 512 rows x 1440 B (720 KB, pure stores) ----
    // Row image lives in registers: slot `lane` (rA) + slot `64+lane` (rB).
    const int wave = tid >> 6;       // 0..7
    const int lane = tid & 63;
    const float4* sG4 = (const float4*)sG;      // 90 float4
    float4 rA = sG4[lane];
    float4 rB; rB.x = 0.f; rB.y = 0.f; rB.z = 0.f; rB.w = 0.f;
    if (lane < 26) rB = sG4[64 + lane];

    float* obase = out + (size_t)nt * FD * LD;
    for (int r = wave; r < FD; r += 8) {        // 64 rows per wave
        float4* row = (float4*)(obase + (size_t)r * LD);
        row[lane] = rA;                          // 1024 B contiguous
        if (lane < 26) row[64 + lane] = rB;      // 416 B contiguous
    }
}

extern "C" void kernel_launch(void* const* d_in, const int* in_sizes, int n_in,
                              void* d_out, int out_size, void* d_ws, size_t ws_size,
                              hipStream_t stream) {
    (void)in_sizes; (void)n_in; (void)out_size; (void)d_ws; (void)ws_size;
    // setup_inputs order: value, key, query, Wv, Wk, Wq, Wo, bo
    const float* value = (const float*)d_in[0];
    const float* Wv    = (const float*)d_in[3];
    const float* Wo    = (const float*)d_in[6];
    const float* bo    = (const float*)d_in[7];
    float* out = (float*)d_out;

    fused_attn<<<dim3(NT), dim3(512), 0, stream>>>(value, Wv, Wo, bo, out);
}